// Round 6
// baseline (79.462 us; speedup 1.0000x reference)
//
#include <hip/hip_runtime.h>
#include <stdint.h>

// rotate-left via v_alignbit_b32 (1 instruction)
__device__ __forceinline__ uint32_t rotl(uint32_t v, int r) {
  return __builtin_amdgcn_alignbit(v, v, (uint32_t)(32 - r));
}

// ---------------- Threefry-2x32, 20 rounds (host copy for key derivation) --
__host__ __device__ inline void tf2x32(uint32_t k0, uint32_t k1,
                                       uint32_t x0, uint32_t x1,
                                       uint32_t& o0, uint32_t& o1) {
  uint32_t k2 = k0 ^ k1 ^ 0x1BD11BDAu;
#define TFR(r) { x0 += x1; x1 = (x1 << (r)) | (x1 >> (32 - (r))); x1 ^= x0; }
  x0 += k0; x1 += k1;
  TFR(13) TFR(15) TFR(26) TFR(6)  x0 += k1; x1 += k2 + 1u;
  TFR(17) TFR(29) TFR(16) TFR(24) x0 += k2; x1 += k0 + 2u;
  TFR(13) TFR(15) TFR(26) TFR(6)  x0 += k0; x1 += k1 + 3u;
  TFR(17) TFR(29) TFR(16) TFR(24) x0 += k1; x1 += k2 + 4u;
  TFR(13) TFR(15) TFR(26) TFR(6)  x0 += k2; x1 += k0 + 5u;
#undef TFR
  o0 = x0; o1 = x1;
}

// 8-chain lockstep threefry, chains at counter (0, jb + STRIDE*i).
// out[i] = o0^o1 (JAX partitionable random_bits). Key injections fused into
// the following round's add (v_add3), round-1 add merged into init.
template <unsigned STRIDE>
__device__ __forceinline__ void tf8(uint32_t k0, uint32_t k1, uint32_t jb,
                                    uint32_t out[8]) {
  uint32_t k2 = k0 ^ k1 ^ 0x1BD11BDAu;
  uint32_t k21 = k2 + 1u, k02 = k0 + 2u, k13 = k1 + 3u, k24 = k2 + 4u,
           k05 = k0 + 5u;
  uint32_t a[8], b[8];
  uint32_t jk = jb + k1;
#pragma unroll
  for (int i = 0; i < 8; ++i) {
    b[i] = jk + STRIDE * (unsigned)i;   // literal offset
    a[i] = k0 + b[i];                   // round-1 "a += b" merged with a = k0
  }
#pragma unroll
  for (int i = 0; i < 8; ++i) b[i] = rotl(b[i], 13) ^ a[i];  // round-1 tail
#define RND8(r)                                                        \
  _Pragma("unroll") for (int i = 0; i < 8; ++i) {                      \
    a[i] += b[i];                                                      \
    b[i] = rotl(b[i], (r)) ^ a[i];                                     \
  }
#define RNDI8(r, ka, kbn)                                              \
  _Pragma("unroll") for (int i = 0; i < 8; ++i) {                      \
    b[i] += (kbn);                                                     \
    a[i] = a[i] + (ka) + b[i];  /* v_add3_u32 */                       \
    b[i] = rotl(b[i], (r)) ^ a[i];                                     \
  }
  RND8(15) RND8(26) RND8(6)
  RNDI8(17, k1, k21) RND8(29) RND8(16) RND8(24)
  RNDI8(13, k2, k02) RND8(15) RND8(26) RND8(6)
  RNDI8(17, k0, k13) RND8(29) RND8(16) RND8(24)
  RNDI8(13, k1, k24) RND8(15) RND8(26) RND8(6)
#undef RND8
#undef RNDI8
#pragma unroll
  for (int i = 0; i < 8; ++i) out[i] = (a[i] + k2) ^ (b[i] + k05);
}

// bits -> float in [0,1): (bits>>9)|0x3F800000 bitcast - 1.0 (JAX _uniform)
__device__ __forceinline__ float bits_to_f01(uint32_t b) {
  return __uint_as_float((b >> 9) | 0x3F800000u) - 1.0f;
}

// order-preserving float<->uint encode for atomicMin on floats
__device__ __forceinline__ unsigned encf(float f) {
  unsigned u = __float_as_uint(f);
  return (u & 0x80000000u) ? ~u : (u | 0x80000000u);
}
__device__ __forceinline__ float decf(unsigned u) {
  unsigned b = (u & 0x80000000u) ? (u & 0x7FFFFFFFu) : ~u;
  return __uint_as_float(b);
}

// ---------------- prep: argmax over 80 class channels + per-tensor min -----
__global__ __launch_bounds__(256) void prep_all(
    const float* __restrict__ x0, const float* __restrict__ x1,
    const float* __restrict__ x2, int* __restrict__ m0, int* __restrict__ m1,
    int* __restrict__ m2, unsigned* __restrict__ mins) {
  unsigned bid = blockIdx.x;
  const float* x; int* midx; unsigned* mE; unsigned N; unsigned lb;
  if (bid < 200u)      { x = x0; midx = m0; mE = mins;     N = 25600u; lb = bid; }
  else if (bid < 250u) { x = x1; midx = m1; mE = mins + 1; N = 6400u;  lb = bid - 200u; }
  else                 { x = x2; midx = m2; mE = mins + 2; N = 1600u;  lb = bid - 250u; }
  unsigned p = lb * 128u + (threadIdx.x >> 1);
  unsigned h = threadIdx.x & 1u;           // half: channels 40h .. 40h+39
  float best = -INFINITY, mn = INFINITY;
  int bi = 0;
  if (p < N) {
    const float* pp = x + (5u + 40u * h) * N + p;
#pragma unroll 8
    for (int k = 0; k < 40; ++k) {
      float v = pp[(unsigned)k * N];
      if (v > best) { best = v; bi = (int)(40u * h) + k; }  // '>': first max
      mn = fminf(mn, v);
    }
  }
  float ob = __shfl_xor(best, 1, 64);
  int obi = __shfl_xor(bi, 1, 64);
  float omn = __shfl_xor(mn, 1, 64);
  float bE = (h == 0u) ? best : ob;  int iE = (h == 0u) ? bi : obi;
  float bO = (h == 0u) ? ob : best;  int iO = (h == 0u) ? obi : bi;
  int mbi = (bO > bE) ? iO : iE;     // ties -> lower-k half (first max)
  mn = fminf(mn, omn);
  if (h == 0u && p < N) midx[p] = mbi;
  unsigned u = encf(mn);
  for (int off = 32; off > 0; off >>= 1) {
    unsigned o = __shfl_down(u, (unsigned)off, 64);
    u = (o < u) ? o : u;
  }
  if ((threadIdx.x & 63u) == 0u) atomicMin(mE, u);
}

// ---------------- fused main: scatter-replace (batch 0) + gaussian noise ----
struct TP {
  const float* x;
  float* out;
  const int* midx;
  uint32_t uk0, uk1, nk0, nk1;
  unsigned k;        // N = 25 << k
  unsigned N;
  unsigned tot;      // 680 * N
  unsigned blk_end;  // exclusive prefix sum of block counts
};

__global__ __launch_bounds__(256, 8) void main_all(
    TP p0, TP p1, TP p2, const unsigned* __restrict__ mins,
    const float* __restrict__ valuep) {
  unsigned bid = blockIdx.x;
  TP P; unsigned t;
  if (bid < p0.blk_end)      { P = p0; t = 0u; }
  else if (bid < p1.blk_end) { P = p1; t = 1u; bid -= p0.blk_end; }
  else                       { P = p2; t = 2u; bid -= p1.blk_end; }

  unsigned i0 = (bid * 256u + threadIdx.x) * 8u;   // 8 elements per thread
  if (i0 >= P.tot) return;

  // bc = i0 / N via (i0 >> k) / 25 (magic); b,c from bc < 680
  unsigned bc = __umulhi(i0 >> P.k, 0x51EB851Fu) >> 3;
  unsigned n0 = i0 - bc * P.N;         // 8 consecutive n, same (b,c)
  unsigned b = (bc * 772u) >> 16;      // exact for bc < 680
  unsigned c = bc - b * 85u;

  // ---- issue ALL loads before the long compute (latency fully hidden) ----
  float4 va = *reinterpret_cast<const float4*>(P.x + i0);
  float4 vb = *reinterpret_cast<const float4*>(P.x + i0 + 4);
  int4 ma = *reinterpret_cast<const int4*>(P.midx + n0);        // L2-hot
  int4 mb4 = *reinterpret_cast<const int4*>(P.midx + n0 + 4);
  float clsmin = decf(mins[t]);
  float value = *valuep;
  float sv = value * 1.41421356237309515f;

  // ---- noise bits: 8 lockstep threefry chains ----
  unsigned jb = (b * P.N + n0) * 85u + c;   // noise array [B,N,C] flat index
  uint32_t nb[8];
  tf8<85u>(P.nk0, P.nk1, jb, nb);

  // ---- zlite, coefficient-major lockstep over 8 values ----
  const float lo = __uint_as_float(0xBF7FFFFFu);  // nextafter(-1.f, 0.f)
  float x8[8], L8[8], t8[8], p8[8], nz[8];
#pragma unroll
  for (int q = 0; q < 8; ++q) {
    float f = __uint_as_float((nb[q] >> 9) | 0x3F800000u) - 1.0f;
    x8[q] = fmaxf(lo, fmaf(f, 2.0f, lo));
  }
#pragma unroll
  for (int q = 0; q < 8; ++q) L8[q] = __log2f(fmaf(-x8[q], x8[q], 1.0f));
#pragma unroll
  for (int q = 0; q < 8; ++q) t8[q] = fmaf(L8[q], -0.69314718f, -2.5f);
#pragma unroll
  for (int q = 0; q < 8; ++q) p8[q] = fmaf(0.00021858087f, t8[q], -0.00125372503f);
#pragma unroll
  for (int q = 0; q < 8; ++q) p8[q] = fmaf(p8[q], t8[q], -0.00417768164f);
#pragma unroll
  for (int q = 0; q < 8; ++q) p8[q] = fmaf(p8[q], t8[q], 0.246640727f);
#pragma unroll
  for (int q = 0; q < 8; ++q) p8[q] = fmaf(p8[q], t8[q], 1.50140941f);
#pragma unroll
  for (int q = 0; q < 8; ++q) {
    // tail (w>=5, 0.34% lanes): linear in w; err <= 0.0045 in output (budget .108)
    float pt = fmaf(L8[q], -0.1113356f, 1.327237f);
    p8[q] = (L8[q] > -7.2134752f) ? p8[q] : pt;
    nz[q] = p8[q] * x8[q];
  }

  float vv[8] = {va.x, va.y, va.z, va.w, vb.x, vb.y, vb.z, vb.w};

  // ---- class scatter-replace (batch 0, channels 5..84) ----
  if (b == 0u && c >= 5u) {
    unsigned kk = c - 5u;
    int mm[8] = {ma.x, ma.y, ma.z, ma.w, mb4.x, mb4.y, mb4.z, mb4.w};
    uint32_t ub[8];
    tf8<80u>(P.uk0, P.uk1, n0 * 80u + kk, ub);   // uniform array [N,80]
#pragma unroll
    for (int q = 0; q < 8; ++q) {
      if ((unsigned)mm[q] != kk) vv[q] = bits_to_f01(ub[q]) * clsmin;
    }
  }

#pragma unroll
  for (int q = 0; q < 8; ++q) vv[q] = fmaf(nz[q], sv, vv[q]);
  *reinterpret_cast<float4*>(P.out + i0) = make_float4(vv[0], vv[1], vv[2], vv[3]);
  *reinterpret_cast<float4*>(P.out + i0 + 4) = make_float4(vv[4], vv[5], vv[6], vv[7]);
}

extern "C" void kernel_launch(void* const* d_in, const int* in_sizes, int n_in,
                              void* d_out, int out_size, void* d_ws, size_t ws_size,
                              hipStream_t stream) {
  const float* xs[3] = {(const float*)d_in[0], (const float*)d_in[1], (const float*)d_in[2]};
  const float* valuep = (const float*)d_in[3];
  float* out = (float*)d_out;

  const unsigned Ns[3] = {25600u, 6400u, 1600u};
  const unsigned ks[3] = {10u, 8u, 6u};   // N = 25 << k

  // workspace: midx0 | midx1 | midx2 | mins[3]
  int* midx[3];
  midx[0] = (int*)d_ws;
  midx[1] = midx[0] + Ns[0];
  midx[2] = midx[1] + Ns[1];
  unsigned* mins = (unsigned*)(midx[2] + Ns[2]);
  hipMemsetAsync(mins, 0xFF, 3 * sizeof(unsigned), stream);

  // Host-side key derivation (partitionable threefry):
  //   base = key(42) = (0,42); key_i = threefry(base,(0,i));
  //   split(key_i) -> k1 = threefry(key_i,(0,0)) [uniform], k2 = threefry(key_i,(0,1)) [normal]
  TP p[3];
  unsigned blk_acc = 0;
  float* outp = out;
  for (int i = 0; i < 3; ++i) {
    uint32_t f0, f1;
    tf2x32(0u, 42u, 0u, (uint32_t)i, f0, f1);
    tf2x32(f0, f1, 0u, 0u, p[i].uk0, p[i].uk1);
    tf2x32(f0, f1, 0u, 1u, p[i].nk0, p[i].nk1);
    p[i].x = xs[i];
    p[i].out = outp;
    p[i].midx = midx[i];
    p[i].k = ks[i];
    p[i].N = Ns[i];
    p[i].tot = 680u * Ns[i];
    blk_acc += (p[i].tot / 8u + 255u) / 256u;
    p[i].blk_end = blk_acc;
    outp += (size_t)680 * Ns[i];
  }

  prep_all<<<263, 256, 0, stream>>>(xs[0], xs[1], xs[2], midx[0], midx[1], midx[2], mins);
  main_all<<<blk_acc, 256, 0, stream>>>(p[0], p[1], p[2], mins, valuep);
}